// Round 3
// baseline (14981.602 us; speedup 1.0000x reference)
//
#include <hip/hip_runtime.h>

#define B_ 256
#define T_ 256
#define H_ 300
#define IN_ 16
#define NT_ 75          // gate tiles (1200/16)
#define KSR_ 10         // recurrent K slabs (300 -> 320)
#define HP_ 320         // padded h row stride (elements)
#define MEMB_ 8         // blocks per batch group (N-split)
#define WPB_ 10         // waves per block

typedef __attribute__((ext_vector_type(8))) short short8;
typedef __attribute__((ext_vector_type(4))) float f32x4;
typedef unsigned int uint32;

__device__ __forceinline__ unsigned short f2bf(float f) {
    uint32 u = __float_as_uint(f);
    u = u + 0x7fffu + ((u >> 16) & 1u);   // RNE
    return (unsigned short)(u >> 16);
}
__device__ __forceinline__ float bf2f(unsigned short h) {
    return __uint_as_float(((uint32)h) << 16);
}
__device__ __forceinline__ float sigm(float x) {
    float e = __expf(-x);
    return __builtin_amdgcn_rcpf(1.f + e);
}
__device__ __forceinline__ float tanh_f(float x) {
    float xc = fminf(fmaxf(x, -15.f), 15.f);
    float e = __expf(2.f * xc);
    return (e - 1.f) * __builtin_amdgcn_rcpf(e + 1.f);
}

// ---------------------------------------------------------------------------
// Weight packing into bf16 MFMA A-fragments, gate rows permuted unit-major.
// Packed row p = 4*jj + gamma  <->  original row r = gamma*300 + jj.
// frag[(tile*KS + slab)*64 + lane] (16B) = W'[tile*16+(lane&15)][slab*32+(lane>>4)*8 + 0..7]
// ---------------------------------------------------------------------------
__device__ __forceinline__ void pack_one(int idx, const float* __restrict__ W,
                                         int K, int KS, uint32* __restrict__ dst)
{
    int lane = idx & 63, ts = idx >> 6;
    int slab = ts % KS, tile = ts / KS;
    int rp = tile * 16 + (lane & 15);
    int jj = rp >> 2, g = rp & 3;
    int r = g * H_ + jj;
    int kb = slab * 32 + (lane >> 4) * 8;
    #pragma unroll
    for (int p = 0; p < 4; ++p) {
        int k0 = kb + 2 * p, k1 = k0 + 1;
        float v0 = (k0 < K) ? W[(size_t)r * K + k0] : 0.f;
        float v1 = (k1 < K) ? W[(size_t)r * K + k1] : 0.f;
        dst[(size_t)idx * 4 + p] = (uint32)f2bf(v0) | ((uint32)f2bf(v1) << 16);
    }
}

__global__ void pack_kernel(const float* __restrict__ Wih0, const float* __restrict__ Whh0,
                            const float* __restrict__ bih0, const float* __restrict__ bhh0,
                            const float* __restrict__ Wih1, const float* __restrict__ Whh1,
                            const float* __restrict__ bih1, const float* __restrict__ bhh1,
                            uint32* __restrict__ wr0, uint32* __restrict__ wg0,
                            uint32* __restrict__ wr1, uint32* __restrict__ wg1,
                            float* __restrict__ b0p, float* __restrict__ b1p)
{
    const int C0 = NT_ * KSR_ * 64;   // 48000
    const int C1 = NT_ * 64;          // 4800
    int id = blockIdx.x * 256 + threadIdx.x;
    if (id < C0) pack_one(id, Whh0, H_, KSR_, wr0);
    else if (id < C0 + C1) pack_one(id - C0, Wih0, IN_, 1, wg0);
    else if (id < 2 * C0 + C1) pack_one(id - C0 - C1, Whh1, H_, KSR_, wr1);
    else if (id < 3 * C0 + C1) pack_one(id - 2 * C0 - C1, Wih1, H_, KSR_, wg1);
    else if (id < 3 * C0 + C1 + 1200) {
        int p = id - 3 * C0 - C1;
        int jj = p >> 2, g = p & 3, r = g * H_ + jj;
        b0p[p] = bih0[r] + bhh0[r];
    } else if (id < 3 * C0 + C1 + 2400) {
        int p = id - 3 * C0 - C1 - 1200;
        int jj = p >> 2, g = p & 3, r = g * H_ + jj;
        b1p[p] = bih1[r] + bhh1[r];
    }
}

// ---------------------------------------------------------------------------
// xg GEMM layer 0 (K=16): xg[(g*TC+tc)*NT + n][lane] = bias + Wih0 @ x_t
// ---------------------------------------------------------------------------
__global__ __launch_bounds__(256) void gemm_xg0(
    const float* __restrict__ x, const short8* __restrict__ wgp,
    const float* __restrict__ bp, f32x4* __restrict__ xg, int t0, int TC)
{
    const int tc = blockIdx.x, g = blockIdx.y;
    const int wave = threadIdx.x >> 6, lane = threadIdx.x & 63;
    const int m = lane & 15, oct = lane >> 4;

    short8 a0;
    if (oct < 2) {
        const float* xr = x + ((size_t)(g * 16 + m) * T_ + (t0 + tc)) * IN_ + oct * 8;
        short8 v;
        #pragma unroll
        for (int e = 0; e < 8; ++e) v[e] = (short)f2bf(xr[e]);
        a0 = v;
    } else {
        short8 z = {0, 0, 0, 0, 0, 0, 0, 0};
        a0 = z;
    }
    f32x4* xq = xg + ((size_t)g * TC + tc) * NT_ * 64 + lane;
    #pragma unroll
    for (int ti = 0; ti < 19; ++ti) {
        int n = wave + 4 * ti;
        if (n >= NT_) continue;
        f32x4 acc = *(const f32x4*)&bp[n * 16 + oct * 4];
        acc = __builtin_amdgcn_mfma_f32_16x16x32_bf16(wgp[(size_t)n * 64 + lane], a0, acc, 0, 0, 0);
        xq[(size_t)n * 64] = acc;
    }
}

// ---------------------------------------------------------------------------
// xg GEMM layer 1 (K=300): 4 waves/block = 4 timesteps sharing one weight
// stream through L1. grid (TC/4, 16).
// ---------------------------------------------------------------------------
__global__ __launch_bounds__(256) void gemm_xg1(
    const unsigned short* __restrict__ hin, const short8* __restrict__ wgp,
    const float* __restrict__ bp, f32x4* __restrict__ xg, int TC)
{
    const int wave = threadIdx.x >> 6, lane = threadIdx.x & 63;
    const int g = blockIdx.y, tc = blockIdx.x * 4 + wave;
    const int m = lane & 15, oct = lane >> 4;

    const unsigned short* hr = hin + ((size_t)(g * 16 + m) * TC + tc) * HP_ + oct * 8;
    short8 a[KSR_];
    #pragma unroll
    for (int s = 0; s < KSR_; ++s) a[s] = *(const short8*)(hr + s * 32);

    f32x4* xq = xg + ((size_t)g * TC + tc) * NT_ * 64 + lane;
    for (int n = 0; n < NT_; ++n) {
        f32x4 acc = *(const f32x4*)&bp[n * 16 + oct * 4];
        #pragma unroll
        for (int s = 0; s < KSR_; ++s)
            acc = __builtin_amdgcn_mfma_f32_16x16x32_bf16(wgp[((size_t)n * KSR_ + s) * 64 + lane],
                                                          a[s], acc, 0, 0, 0);
        xq[(size_t)n * 64] = acc;
    }
}

// ---------------------------------------------------------------------------
// Recurrent LSTM chunk, N-split: 128 blocks x 640 threads.
// blockIdx = member*16 + g  (so a group's 8 members share one XCD under
// round-robin xcd = blockIdx%8). Wave w of member b owns tile b*10+w; its
// Whh slice (10 slabs = 40 VGPRs) is loaded ONCE and pinned in registers.
// Per step: MFMA from regs -> epilogue -> write h slice to global fragment
// buffer hx[g][gt&1] -> barrier -> block arrive on monotonic counter ->
// all waves acquire-spin (buffer_inv) -> plain coalesced reload of h.
// ---------------------------------------------------------------------------
__global__ __launch_bounds__(640, 3) void lstm_rec(
    const short8* __restrict__ wp, const f32x4* __restrict__ xg,
    unsigned short* __restrict__ hout, float* __restrict__ cbuf,
    unsigned short* __restrict__ hx, int* __restrict__ cnt,
    int t0, int TC, size_t rowstride_b, int tbase)
{
    const int tid = threadIdx.x;
    const int wave = tid >> 6, lane = tid & 63;
    const int g = blockIdx.x & 15, member = blockIdx.x >> 4;
    const int wtile = member * WPB_ + wave;
    const bool act = (wtile < NT_);
    const int m = lane & 15, oct = lane >> 4;

    int* cg = cnt + g * 16;                       // 64B-strided counters
    unsigned short* hxg = hx + (size_t)g * 2 * 5120;

    // pinned weights (loop-invariant; stays in VGPRs)
    short8 w[KSR_];
    if (act) {
        #pragma unroll
        for (int s = 0; s < KSR_; ++s) w[s] = wp[((size_t)wtile * KSR_ + s) * 64 + lane];
    }
    float c = 0.f;
    if (act && t0 > 0) c = cbuf[((size_t)g * 80 + wtile) * 64 + lane];

    // initial h fragments = h_{t0-1}, always slot 1 (TC even; t0==0 slot is
    // zeroed by the in-graph memset). Kernel-entry acquire makes it fresh.
    short8 a[KSR_];
    {
        const short8* hsrc = (const short8*)(hxg + 5120);
        #pragma unroll
        for (int s = 0; s < KSR_; ++s) a[s] = hsrc[s * 64 + lane];
    }

    const f32x4* xgp = xg + ((size_t)g * TC * NT_ + wtile) * 64 + lane;
    const int jj = wtile * 4 + oct;
    const int fragaddr = (((jj >> 5) * 64 + ((jj >> 3) & 3) * 16 + m) << 3) + (jj & 7);
    unsigned short* houtp = hout + (size_t)(g * 16 + m) * rowstride_b
                          + (size_t)tbase * HP_ + jj;

    for (int tc_ = 0; tc_ < TC; ++tc_) {
        const int gt = t0 + tc_;
        if (act) {
            f32x4 xgv = xgp[(size_t)tc_ * NT_ * 64];
            f32x4 acc0 = {0.f, 0.f, 0.f, 0.f};
            f32x4 acc1 = {0.f, 0.f, 0.f, 0.f};
            #pragma unroll
            for (int s = 0; s < KSR_; s += 2) {
                acc0 = __builtin_amdgcn_mfma_f32_16x16x32_bf16(w[s],     a[s],     acc0, 0, 0, 0);
                acc1 = __builtin_amdgcn_mfma_f32_16x16x32_bf16(w[s + 1], a[s + 1], acc1, 0, 0, 0);
            }
            float gi = sigm(acc0[0] + acc1[0] + xgv[0]);
            float gf = sigm(acc0[1] + acc1[1] + xgv[1]);
            float gg = tanh_f(acc0[2] + acc1[2] + xgv[2]);
            float go = sigm(acc0[3] + acc1[3] + xgv[3]);
            float cn = gf * c + gi * gg;
            c = cn;
            unsigned short hb = f2bf(go * tanh_f(cn));
            hxg[(gt & 1) * 5120 + fragaddr] = hb;
            houtp[(size_t)tc_ * HP_] = hb;
        }
        __syncthreads();   // drains each wave's stores (vmcnt0) before arrive
        if (tid == 0)
            __hip_atomic_fetch_add(cg, 1, __ATOMIC_RELEASE, __HIP_MEMORY_SCOPE_AGENT);
        if (tc_ + 1 < TC) {
            const int target = MEMB_ * (gt + 1);
            int iters = 0;
            while (__hip_atomic_load(cg, __ATOMIC_ACQUIRE, __HIP_MEMORY_SCOPE_AGENT) < target) {
                __builtin_amdgcn_s_sleep(1);
                if (++iters > (1 << 22)) break;   // bailout: wrong > hung
            }
            const short8* hsrc = (const short8*)(hxg + (gt & 1) * 5120);
            #pragma unroll
            for (int s = 0; s < KSR_; ++s) a[s] = hsrc[s * 64 + lane];
        }
    }
    if (act) cbuf[((size_t)g * 80 + wtile) * 64 + lane] = c;
}

// ---------------------------------------------------------------------------
// MLP head: per-thread position; weights uniform (L1/L2-cached).
// ---------------------------------------------------------------------------
__global__ __launch_bounds__(256) void head_kernel(
    const unsigned short* __restrict__ h1,
    const float* __restrict__ W1, const float* __restrict__ b1,
    const float* __restrict__ W2, const float* __restrict__ b2,
    const float* __restrict__ W3, const float* __restrict__ b3,
    float* __restrict__ out)
{
    int pos = blockIdx.x * 256 + threadIdx.x;
    const unsigned short* hr = h1 + (size_t)pos * HP_;
    float t1[30];
    #pragma unroll
    for (int j = 0; j < 30; ++j) t1[j] = b1[j];
    for (int kc = 0; kc < H_; kc += 4) {
        uint32 u0 = *(const uint32*)(hr + kc);
        uint32 u1 = *(const uint32*)(hr + kc + 2);
        float h0v = bf2f((unsigned short)(u0 & 0xffffu));
        float h1v = bf2f((unsigned short)(u0 >> 16));
        float h2v = bf2f((unsigned short)(u1 & 0xffffu));
        float h3v = bf2f((unsigned short)(u1 >> 16));
        #pragma unroll
        for (int j = 0; j < 30; ++j) {
            const float* wr = W1 + j * H_ + kc;
            t1[j] += h0v * wr[0] + h1v * wr[1] + h2v * wr[2] + h3v * wr[3];
        }
    }
    #pragma unroll
    for (int j = 0; j < 30; ++j) t1[j] = tanh_f(t1[j]);
    float oacc = b3[0];
    for (int j2 = 0; j2 < 100; ++j2) {
        float a2 = b2[j2];
        #pragma unroll
        for (int k = 0; k < 30; ++k) a2 += t1[k] * W2[j2 * 30 + k];
        oacc += tanh_f(a2) * W3[j2];
    }
    out[pos] = sigm(oacc);
}

// ---------------------------------------------------------------------------
extern "C" void kernel_launch(void* const* d_in, const int* in_sizes, int n_in,
                              void* d_out, int out_size, void* d_ws, size_t ws_size,
                              hipStream_t stream)
{
    const float* x    = (const float*)d_in[0];
    const float* Wih0 = (const float*)d_in[1];
    const float* Whh0 = (const float*)d_in[2];
    const float* bih0 = (const float*)d_in[3];
    const float* bhh0 = (const float*)d_in[4];
    const float* Wih1 = (const float*)d_in[5];
    const float* Whh1 = (const float*)d_in[6];
    const float* bih1 = (const float*)d_in[7];
    const float* bhh1 = (const float*)d_in[8];
    const float* W1   = (const float*)d_in[9];
    const float* b1   = (const float*)d_in[10];
    const float* W2   = (const float*)d_in[11];
    const float* b2   = (const float*)d_in[12];
    const float* W3   = (const float*)d_in[13];
    const float* b3   = (const float*)d_in[14];

    char* ws = (char*)d_ws;
    const size_t OFF_WR0 = 0x000000;
    const size_t OFF_WG0 = 0x100000;
    const size_t OFF_WR1 = 0x200000;
    const size_t OFF_WG1 = 0x300000;
    const size_t OFF_B0  = 0x400000;
    const size_t OFF_B1  = 0x402000;
    const size_t OFF_CB0 = 0x500000;   // 320KB
    const size_t OFF_CB1 = 0x550000;   // 320KB
    const size_t OFF_HX0 = 0x5A0000;   // 320KB
    const size_t OFF_HX1 = 0x5F0000;   // 320KB
    const size_t OFF_CNT = 0x640000;   // 8KB (cnt0 @ +0, cnt1 @ +4KB)
    const size_t OFF_H1  = 0x700000;
    const size_t H1_BYTES = (size_t)B_ * T_ * HP_ * 2;   // 40 MiB
    const size_t OFF_H0C  = OFF_H1 + H1_BYTES;

    int TC = 0;
    {
        const int cands[4] = {64, 32, 16, 8};
        for (int i = 0; i < 4; ++i) {
            size_t h0cb = (size_t)B_ * cands[i] * HP_ * 2;
            size_t xgb  = (size_t)16 * cands[i] * NT_ * 64 * 16;
            if (OFF_H0C + h0cb + xgb <= ws_size) { TC = cands[i]; break; }
        }
    }
    if (TC == 0) return;
    const size_t OFF_XG = OFF_H0C + (size_t)B_ * TC * HP_ * 2;

    uint32* wr0 = (uint32*)(ws + OFF_WR0);
    uint32* wg0 = (uint32*)(ws + OFF_WG0);
    uint32* wr1 = (uint32*)(ws + OFF_WR1);
    uint32* wg1 = (uint32*)(ws + OFF_WG1);
    float*  b0p = (float*)(ws + OFF_B0);
    float*  b1p = (float*)(ws + OFF_B1);
    float*  cb0 = (float*)(ws + OFF_CB0);
    float*  cb1 = (float*)(ws + OFF_CB1);
    unsigned short* hx0 = (unsigned short*)(ws + OFF_HX0);
    unsigned short* hx1 = (unsigned short*)(ws + OFF_HX1);
    int* cnt0 = (int*)(ws + OFF_CNT);
    int* cnt1 = (int*)(ws + OFF_CNT + 4096);
    unsigned short* h1b = (unsigned short*)(ws + OFF_H1);
    unsigned short* h0c = (unsigned short*)(ws + OFF_H0C);
    f32x4* xgb = (f32x4*)(ws + OFF_XG);

    // in-graph re-init each launch: h exchange slots, counters, h0c pads
    hipMemsetAsync(ws + OFF_HX0, 0, 0x640000 + 8192 - OFF_HX0, stream);
    hipMemsetAsync(ws + OFF_H0C, 0, (size_t)B_ * TC * HP_ * 2, stream);

    hipLaunchKernelGGL(pack_kernel, dim3(591), dim3(256), 0, stream,
                       Wih0, Whh0, bih0, bhh0, Wih1, Whh1, bih1, bhh1,
                       wr0, wg0, wr1, wg1, b0p, b1p);

    for (int t0 = 0; t0 < T_; t0 += TC) {
        hipLaunchKernelGGL(gemm_xg0, dim3(TC, 16), dim3(256), 0, stream,
                           x, (const short8*)wg0, b0p, xgb, t0, TC);
        hipLaunchKernelGGL(lstm_rec, dim3(128), dim3(640), 0, stream,
                           (const short8*)wr0, (const f32x4*)xgb, h0c, cb0, hx0, cnt0,
                           t0, TC, (size_t)TC * HP_, 0);
        hipLaunchKernelGGL(gemm_xg1, dim3(TC / 4, 16), dim3(256), 0, stream,
                           h0c, (const short8*)wg1, b1p, xgb, TC);
        hipLaunchKernelGGL(lstm_rec, dim3(128), dim3(640), 0, stream,
                           (const short8*)wr1, (const f32x4*)xgb, h1b, cb1, hx1, cnt1,
                           t0, TC, (size_t)T_ * HP_, t0);
    }
    hipLaunchKernelGGL(head_kernel, dim3(256), dim3(256), 0, stream,
                       h1b, W1, b1, W2, b2, W3, b3, (float*)d_out);
}

// Round 4
// 4388.126 us; speedup vs baseline: 3.4141x; 3.4141x over previous
//
#include <hip/hip_runtime.h>

#define B_ 256
#define T_ 256
#define H_ 300
#define IN_ 16
#define NT_ 75          // gate tiles (1200/16)
#define KSR_ 10         // recurrent K slabs (300 -> 320)
#define HP_ 320         // padded h row stride (elements)
#define MEMB_ 8         // blocks per batch group (N-split)
#define WPB_ 10         // waves per block

typedef __attribute__((ext_vector_type(8))) short short8;
typedef __attribute__((ext_vector_type(4))) float f32x4;
typedef unsigned int uint32;

#define FORALL10(F) F(0) F(1) F(2) F(3) F(4) F(5) F(6) F(7) F(8) F(9)

__device__ __forceinline__ unsigned short f2bf(float f) {
    uint32 u = __float_as_uint(f);
    u = u + 0x7fffu + ((u >> 16) & 1u);   // RNE
    return (unsigned short)(u >> 16);
}
__device__ __forceinline__ float bf2f(unsigned short h) {
    return __uint_as_float(((uint32)h) << 16);
}
__device__ __forceinline__ float sigm(float x) {
    float e = __expf(-x);
    return __builtin_amdgcn_rcpf(1.f + e);
}
__device__ __forceinline__ float tanh_f(float x) {
    float xc = fminf(fmaxf(x, -15.f), 15.f);
    float e = __expf(2.f * xc);
    return (e - 1.f) * __builtin_amdgcn_rcpf(e + 1.f);
}

// ---------------------------------------------------------------------------
// Weight packing into bf16 MFMA A-fragments, gate rows permuted unit-major.
// Packed row p = 4*jj + gamma  <->  original row r = gamma*300 + jj.
// frag[(tile*KS + slab)*64 + lane] (16B) = W'[tile*16+(lane&15)][slab*32+(lane>>4)*8 + 0..7]
// ---------------------------------------------------------------------------
__device__ __forceinline__ void pack_one(int idx, const float* __restrict__ W,
                                         int K, int KS, uint32* __restrict__ dst)
{
    int lane = idx & 63, ts = idx >> 6;
    int slab = ts % KS, tile = ts / KS;
    int rp = tile * 16 + (lane & 15);
    int jj = rp >> 2, g = rp & 3;
    int r = g * H_ + jj;
    int kb = slab * 32 + (lane >> 4) * 8;
    #pragma unroll
    for (int p = 0; p < 4; ++p) {
        int k0 = kb + 2 * p, k1 = k0 + 1;
        float v0 = (k0 < K) ? W[(size_t)r * K + k0] : 0.f;
        float v1 = (k1 < K) ? W[(size_t)r * K + k1] : 0.f;
        dst[(size_t)idx * 4 + p] = (uint32)f2bf(v0) | ((uint32)f2bf(v1) << 16);
    }
}

__global__ void pack_kernel(const float* __restrict__ Wih0, const float* __restrict__ Whh0,
                            const float* __restrict__ bih0, const float* __restrict__ bhh0,
                            const float* __restrict__ Wih1, const float* __restrict__ Whh1,
                            const float* __restrict__ bih1, const float* __restrict__ bhh1,
                            uint32* __restrict__ wr0, uint32* __restrict__ wg0,
                            uint32* __restrict__ wr1, uint32* __restrict__ wg1,
                            float* __restrict__ b0p, float* __restrict__ b1p)
{
    const int C0 = NT_ * KSR_ * 64;   // 48000
    const int C1 = NT_ * 64;          // 4800
    int id = blockIdx.x * 256 + threadIdx.x;
    if (id < C0) pack_one(id, Whh0, H_, KSR_, wr0);
    else if (id < C0 + C1) pack_one(id - C0, Wih0, IN_, 1, wg0);
    else if (id < 2 * C0 + C1) pack_one(id - C0 - C1, Whh1, H_, KSR_, wr1);
    else if (id < 3 * C0 + C1) pack_one(id - 2 * C0 - C1, Wih1, H_, KSR_, wg1);
    else if (id < 3 * C0 + C1 + 1200) {
        int p = id - 3 * C0 - C1;
        int jj = p >> 2, g = p & 3, r = g * H_ + jj;
        b0p[p] = bih0[r] + bhh0[r];
    } else if (id < 3 * C0 + C1 + 2400) {
        int p = id - 3 * C0 - C1 - 1200;
        int jj = p >> 2, g = p & 3, r = g * H_ + jj;
        b1p[p] = bih1[r] + bhh1[r];
    }
}

// ---------------------------------------------------------------------------
// xg GEMM layer 0 (K=16): xg[(g*TC+tc)*NT + n][lane] = bias + Wih0 @ x_t
// ---------------------------------------------------------------------------
__global__ __launch_bounds__(256) void gemm_xg0(
    const float* __restrict__ x, const short8* __restrict__ wgp,
    const float* __restrict__ bp, f32x4* __restrict__ xg, int t0, int TC)
{
    const int tc = blockIdx.x, g = blockIdx.y;
    const int wave = threadIdx.x >> 6, lane = threadIdx.x & 63;
    const int m = lane & 15, oct = lane >> 4;

    short8 a0;
    if (oct < 2) {
        const float* xr = x + ((size_t)(g * 16 + m) * T_ + (t0 + tc)) * IN_ + oct * 8;
        short8 v;
        #pragma unroll
        for (int e = 0; e < 8; ++e) v[e] = (short)f2bf(xr[e]);
        a0 = v;
    } else {
        short8 z = {0, 0, 0, 0, 0, 0, 0, 0};
        a0 = z;
    }
    f32x4* xq = xg + ((size_t)g * TC + tc) * NT_ * 64 + lane;
    #pragma unroll
    for (int ti = 0; ti < 19; ++ti) {
        int n = wave + 4 * ti;
        if (n >= NT_) continue;
        f32x4 acc = *(const f32x4*)&bp[n * 16 + oct * 4];
        acc = __builtin_amdgcn_mfma_f32_16x16x32_bf16(wgp[(size_t)n * 64 + lane], a0, acc, 0, 0, 0);
        xq[(size_t)n * 64] = acc;
    }
}

// ---------------------------------------------------------------------------
// xg GEMM layer 1 (K=300): 4 waves/block = 4 timesteps sharing one weight
// stream through L1. grid (TC/4, 16).
// ---------------------------------------------------------------------------
__global__ __launch_bounds__(256) void gemm_xg1(
    const unsigned short* __restrict__ hin, const short8* __restrict__ wgp,
    const float* __restrict__ bp, f32x4* __restrict__ xg, int TC)
{
    const int wave = threadIdx.x >> 6, lane = threadIdx.x & 63;
    const int g = blockIdx.y, tc = blockIdx.x * 4 + wave;
    const int m = lane & 15, oct = lane >> 4;

    const unsigned short* hr = hin + ((size_t)(g * 16 + m) * TC + tc) * HP_ + oct * 8;
    short8 a[KSR_];
    #pragma unroll
    for (int s = 0; s < KSR_; ++s) a[s] = *(const short8*)(hr + s * 32);

    f32x4* xq = xg + ((size_t)g * TC + tc) * NT_ * 64 + lane;
    for (int n = 0; n < NT_; ++n) {
        f32x4 acc = *(const f32x4*)&bp[n * 16 + oct * 4];
        #pragma unroll
        for (int s = 0; s < KSR_; ++s)
            acc = __builtin_amdgcn_mfma_f32_16x16x32_bf16(wgp[((size_t)n * KSR_ + s) * 64 + lane],
                                                          a[s], acc, 0, 0, 0);
        xq[(size_t)n * 64] = acc;
    }
}

// ---------------------------------------------------------------------------
// Recurrent LSTM chunk, N-split: 128 blocks x 640 threads.
// blockIdx = member*16 + g. Wave w of member b owns tile b*10+w; its Whh
// slice (10 slabs = 40 VGPRs) is pinned in NAMED registers (w0..w9 -- no
// arrays, so the compiler cannot demote them to scratch). Per step:
// reg-MFMA -> epilogue -> store h slice -> barrier -> tid0 release-add ->
// tid0 acquire-spin (buffer_inv covers the CU's L1) -> barrier -> reload h.
// ---------------------------------------------------------------------------
__global__ __launch_bounds__(640) void lstm_rec(
    const short8* __restrict__ wp, const f32x4* __restrict__ xg,
    unsigned short* __restrict__ hout, float* __restrict__ cbuf,
    unsigned short* __restrict__ hx, int* __restrict__ cnt,
    int t0, int TC, size_t rowstride_b, int tbase)
{
    const int tid = threadIdx.x;
    const int wave = tid >> 6, lane = tid & 63;
    const int g = blockIdx.x & 15, member = blockIdx.x >> 4;
    int wtile = member * WPB_ + wave;
    const bool act = (wtile < NT_);
    if (!act) wtile = NT_ - 1;            // clamp: compute garbage, store nothing
    const int m = lane & 15, oct = lane >> 4;

    int* cg = cnt + g * 16;               // 64B-strided counters
    unsigned short* hxg = hx + (size_t)g * 2 * 5120;

    // pinned weights: named scalars, unconditional restrict-loads -> hoisted
    const short8* wq = wp + (size_t)wtile * KSR_ * 64 + lane;
#define DECLW(i) short8 w##i = wq[i * 64];
    FORALL10(DECLW)
#undef DECLW

    float c = 0.f;
    if (act && t0 > 0) c = cbuf[((size_t)g * 80 + wtile) * 64 + lane];

    // initial h = h_{t0-1}: always slot 1 (TC even; zeroed by memset at t0=0)
    const short8* slot0 = (const short8*)hxg;
    const short8* slot1 = (const short8*)(hxg + 5120);
#define DECLA(i) short8 a##i = slot1[i * 64 + lane];
    FORALL10(DECLA)
#undef DECLA

    const f32x4* xgp = xg + ((size_t)g * TC * NT_ + wtile) * 64 + lane;
    const int jj = wtile * 4 + oct;
    const int fragaddr = (((jj >> 5) * 64 + ((jj >> 3) & 3) * 16 + m) << 3) + (jj & 7);
    unsigned short* houtp = hout + (size_t)(g * 16 + m) * rowstride_b
                          + (size_t)tbase * HP_ + jj;

    for (int tc_ = 0; tc_ < TC; ++tc_) {
        const int gt = t0 + tc_;
        {
            f32x4 xgv = xgp[(size_t)tc_ * NT_ * 64];
            f32x4 acc0 = {0.f, 0.f, 0.f, 0.f};
            f32x4 acc1 = {0.f, 0.f, 0.f, 0.f};
            acc0 = __builtin_amdgcn_mfma_f32_16x16x32_bf16(w0, a0, acc0, 0, 0, 0);
            acc1 = __builtin_amdgcn_mfma_f32_16x16x32_bf16(w1, a1, acc1, 0, 0, 0);
            acc0 = __builtin_amdgcn_mfma_f32_16x16x32_bf16(w2, a2, acc0, 0, 0, 0);
            acc1 = __builtin_amdgcn_mfma_f32_16x16x32_bf16(w3, a3, acc1, 0, 0, 0);
            acc0 = __builtin_amdgcn_mfma_f32_16x16x32_bf16(w4, a4, acc0, 0, 0, 0);
            acc1 = __builtin_amdgcn_mfma_f32_16x16x32_bf16(w5, a5, acc1, 0, 0, 0);
            acc0 = __builtin_amdgcn_mfma_f32_16x16x32_bf16(w6, a6, acc0, 0, 0, 0);
            acc1 = __builtin_amdgcn_mfma_f32_16x16x32_bf16(w7, a7, acc1, 0, 0, 0);
            acc0 = __builtin_amdgcn_mfma_f32_16x16x32_bf16(w8, a8, acc0, 0, 0, 0);
            acc1 = __builtin_amdgcn_mfma_f32_16x16x32_bf16(w9, a9, acc1, 0, 0, 0);
            float gi = sigm(acc0[0] + acc1[0] + xgv[0]);
            float gf = sigm(acc0[1] + acc1[1] + xgv[1]);
            float gg = tanh_f(acc0[2] + acc1[2] + xgv[2]);
            float go = sigm(acc0[3] + acc1[3] + xgv[3]);
            float cn = gf * c + gi * gg;
            c = cn;
            unsigned short hb = f2bf(go * tanh_f(cn));
            if (act) {
                hxg[(gt & 1) * 5120 + fragaddr] = hb;
                houtp[(size_t)tc_ * HP_] = hb;
            }
        }
        __syncthreads();   // each wave's stores drained (vmcnt0) before arrive
        if (tid == 0)
            __hip_atomic_fetch_add(cg, 1, __ATOMIC_RELEASE, __HIP_MEMORY_SCOPE_AGENT);
        if (tc_ + 1 < TC) {
            if (tid == 0) {
                const int target = MEMB_ * (gt + 1);
                int iters = 0;
                while (__hip_atomic_load(cg, __ATOMIC_ACQUIRE, __HIP_MEMORY_SCOPE_AGENT) < target) {
                    __builtin_amdgcn_s_sleep(1);
                    if (++iters > (1 << 22)) break;   // bailout: wrong > hung
                }
            }
            __syncthreads();   // block released only after flag seen (L1 inv'd)
            const short8* hs = (gt & 1) ? slot1 : slot0;
#define RELA(i) a##i = hs[i * 64 + lane];
            FORALL10(RELA)
#undef RELA
        }
    }
    if (act) cbuf[((size_t)g * 80 + wtile) * 64 + lane] = c;
}

// ---------------------------------------------------------------------------
// MLP head: per-thread position; weights uniform (L1/L2-cached).
// ---------------------------------------------------------------------------
__global__ __launch_bounds__(256) void head_kernel(
    const unsigned short* __restrict__ h1,
    const float* __restrict__ W1, const float* __restrict__ b1,
    const float* __restrict__ W2, const float* __restrict__ b2,
    const float* __restrict__ W3, const float* __restrict__ b3,
    float* __restrict__ out)
{
    int pos = blockIdx.x * 256 + threadIdx.x;
    const unsigned short* hr = h1 + (size_t)pos * HP_;
    float t1[30];
    #pragma unroll
    for (int j = 0; j < 30; ++j) t1[j] = b1[j];
    for (int kc = 0; kc < H_; kc += 4) {
        uint32 u0 = *(const uint32*)(hr + kc);
        uint32 u1 = *(const uint32*)(hr + kc + 2);
        float h0v = bf2f((unsigned short)(u0 & 0xffffu));
        float h1v = bf2f((unsigned short)(u0 >> 16));
        float h2v = bf2f((unsigned short)(u1 & 0xffffu));
        float h3v = bf2f((unsigned short)(u1 >> 16));
        #pragma unroll
        for (int j = 0; j < 30; ++j) {
            const float* wr = W1 + j * H_ + kc;
            t1[j] += h0v * wr[0] + h1v * wr[1] + h2v * wr[2] + h3v * wr[3];
        }
    }
    #pragma unroll
    for (int j = 0; j < 30; ++j) t1[j] = tanh_f(t1[j]);
    float oacc = b3[0];
    for (int j2 = 0; j2 < 100; ++j2) {
        float a2 = b2[j2];
        #pragma unroll
        for (int k = 0; k < 30; ++k) a2 += t1[k] * W2[j2 * 30 + k];
        oacc += tanh_f(a2) * W3[j2];
    }
    out[pos] = sigm(oacc);
}

// ---------------------------------------------------------------------------
extern "C" void kernel_launch(void* const* d_in, const int* in_sizes, int n_in,
                              void* d_out, int out_size, void* d_ws, size_t ws_size,
                              hipStream_t stream)
{
    const float* x    = (const float*)d_in[0];
    const float* Wih0 = (const float*)d_in[1];
    const float* Whh0 = (const float*)d_in[2];
    const float* bih0 = (const float*)d_in[3];
    const float* bhh0 = (const float*)d_in[4];
    const float* Wih1 = (const float*)d_in[5];
    const float* Whh1 = (const float*)d_in[6];
    const float* bih1 = (const float*)d_in[7];
    const float* bhh1 = (const float*)d_in[8];
    const float* W1   = (const float*)d_in[9];
    const float* b1   = (const float*)d_in[10];
    const float* W2   = (const float*)d_in[11];
    const float* b2   = (const float*)d_in[12];
    const float* W3   = (const float*)d_in[13];
    const float* b3   = (const float*)d_in[14];

    char* ws = (char*)d_ws;
    const size_t OFF_WR0 = 0x000000;
    const size_t OFF_WG0 = 0x100000;
    const size_t OFF_WR1 = 0x200000;
    const size_t OFF_WG1 = 0x300000;
    const size_t OFF_B0  = 0x400000;
    const size_t OFF_B1  = 0x402000;
    const size_t OFF_CB0 = 0x500000;   // 320KB
    const size_t OFF_CB1 = 0x550000;   // 320KB
    const size_t OFF_HX0 = 0x5A0000;   // 320KB
    const size_t OFF_HX1 = 0x5F0000;   // 320KB
    const size_t OFF_CNT = 0x640000;   // 8KB (cnt0 @ +0, cnt1 @ +4KB)
    const size_t OFF_H1  = 0x700000;
    const size_t H1_BYTES = (size_t)B_ * T_ * HP_ * 2;   // 40 MiB
    const size_t OFF_H0C  = OFF_H1 + H1_BYTES;

    int TC = 0;
    {
        const int cands[4] = {64, 32, 16, 8};
        for (int i = 0; i < 4; ++i) {
            size_t h0cb = (size_t)B_ * cands[i] * HP_ * 2;
            size_t xgb  = (size_t)16 * cands[i] * NT_ * 64 * 16;
            if (OFF_H0C + h0cb + xgb <= ws_size) { TC = cands[i]; break; }
        }
    }
    if (TC == 0) return;
    const size_t OFF_XG = OFF_H0C + (size_t)B_ * TC * HP_ * 2;

    uint32* wr0 = (uint32*)(ws + OFF_WR0);
    uint32* wg0 = (uint32*)(ws + OFF_WG0);
    uint32* wr1 = (uint32*)(ws + OFF_WR1);
    uint32* wg1 = (uint32*)(ws + OFF_WG1);
    float*  b0p = (float*)(ws + OFF_B0);
    float*  b1p = (float*)(ws + OFF_B1);
    float*  cb0 = (float*)(ws + OFF_CB0);
    float*  cb1 = (float*)(ws + OFF_CB1);
    unsigned short* hx0 = (unsigned short*)(ws + OFF_HX0);
    unsigned short* hx1 = (unsigned short*)(ws + OFF_HX1);
    int* cnt0 = (int*)(ws + OFF_CNT);
    int* cnt1 = (int*)(ws + OFF_CNT + 4096);
    unsigned short* h1b = (unsigned short*)(ws + OFF_H1);
    unsigned short* h0c = (unsigned short*)(ws + OFF_H0C);
    f32x4* xgb = (f32x4*)(ws + OFF_XG);

    // in-graph re-init each launch: h exchange slots, counters, h0c pads
    hipMemsetAsync(ws + OFF_HX0, 0, 0x640000 + 8192 - OFF_HX0, stream);
    hipMemsetAsync(ws + OFF_H0C, 0, (size_t)B_ * TC * HP_ * 2, stream);

    hipLaunchKernelGGL(pack_kernel, dim3(591), dim3(256), 0, stream,
                       Wih0, Whh0, bih0, bhh0, Wih1, Whh1, bih1, bhh1,
                       wr0, wg0, wr1, wg1, b0p, b1p);

    for (int t0 = 0; t0 < T_; t0 += TC) {
        hipLaunchKernelGGL(gemm_xg0, dim3(TC, 16), dim3(256), 0, stream,
                           x, (const short8*)wg0, b0p, xgb, t0, TC);
        hipLaunchKernelGGL(lstm_rec, dim3(128), dim3(640), 0, stream,
                           (const short8*)wr0, (const f32x4*)xgb, h0c, cb0, hx0, cnt0,
                           t0, TC, (size_t)TC * HP_, 0);
        hipLaunchKernelGGL(gemm_xg1, dim3(TC / 4, 16), dim3(256), 0, stream,
                           h0c, (const short8*)wg1, b1p, xgb, TC);
        hipLaunchKernelGGL(lstm_rec, dim3(128), dim3(640), 0, stream,
                           (const short8*)wr1, (const f32x4*)xgb, h1b, cb1, hx1, cnt1,
                           t0, TC, (size_t)T_ * HP_, t0);
    }
    hipLaunchKernelGGL(head_kernel, dim3(256), dim3(256), 0, stream,
                       h1b, W1, b1, W2, b2, W3, b3, (float*)d_out);
}

// Round 5
// 1858.944 us; speedup vs baseline: 8.0592x; 2.3605x over previous
//
#include <hip/hip_runtime.h>

#define B_ 256
#define T_ 256
#define H_ 300
#define IN_ 16
#define NT_ 75          // gate tiles (1200/16)
#define KSR_ 10         // recurrent K slabs (300 -> 320)
#define HP_ 320         // padded h row stride (elements)
#define MEMB_ 8         // blocks per batch group (N-split)
#define WPB_ 10         // waves per block

typedef __attribute__((ext_vector_type(8))) short short8;
typedef __attribute__((ext_vector_type(4))) float f32x4;
typedef unsigned int uint32;

#define FORALL10(F) F(0) F(1) F(2) F(3) F(4) F(5) F(6) F(7) F(8) F(9)

__device__ __forceinline__ unsigned short f2bf(float f) {
    uint32 u = __float_as_uint(f);
    u = u + 0x7fffu + ((u >> 16) & 1u);   // RNE
    return (unsigned short)(u >> 16);
}
__device__ __forceinline__ float bf2f(unsigned short h) {
    return __uint_as_float(((uint32)h) << 16);
}
__device__ __forceinline__ float sigm(float x) {
    float e = __expf(-x);
    return __builtin_amdgcn_rcpf(1.f + e);
}
__device__ __forceinline__ float tanh_f(float x) {
    float xc = fminf(fmaxf(x, -15.f), 15.f);
    float e = __expf(2.f * xc);
    return (e - 1.f) * __builtin_amdgcn_rcpf(e + 1.f);
}

// --- coherence-point (IF$) ops: bypass L1/L2, NO cache wb/inv anywhere -----
__device__ __forceinline__ short8 load16_cg(const short8* p) {
    short8 r;
    asm volatile("global_load_dwordx4 %0, %1, off sc0 sc1\n\ts_waitcnt vmcnt(0)"
                 : "=v"(r) : "v"(p) : "memory");
    return r;
}
__device__ __forceinline__ int load_cnt_cg(const int* p) {
    int r;
    asm volatile("global_load_dword %0, %1, off sc0 sc1\n\ts_waitcnt vmcnt(0)"
                 : "=v"(r) : "v"(p) : "memory");
    return r;
}
__device__ __forceinline__ void store_short_cg(unsigned short* p, unsigned short v) {
    uint32 vv = v;
    asm volatile("global_store_short %0, %1, off sc0 sc1" :: "v"(p), "v"(vv) : "memory");
}
__device__ __forceinline__ void atomic_inc_cg(int* p) {
    int one = 1;
    asm volatile("global_atomic_add %0, %1, off sc1" :: "v"(p), "v"(one) : "memory");
}

// ---------------------------------------------------------------------------
// Weight packing into bf16 MFMA A-fragments, gate rows permuted unit-major.
// Packed row p = 4*jj + gamma  <->  original row r = gamma*300 + jj.
// frag[(tile*KS + slab)*64 + lane] (16B) = W'[tile*16+(lane&15)][slab*32+(lane>>4)*8 + 0..7]
// ---------------------------------------------------------------------------
__device__ __forceinline__ void pack_one(int idx, const float* __restrict__ W,
                                         int K, int KS, uint32* __restrict__ dst)
{
    int lane = idx & 63, ts = idx >> 6;
    int slab = ts % KS, tile = ts / KS;
    int rp = tile * 16 + (lane & 15);
    int jj = rp >> 2, g = rp & 3;
    int r = g * H_ + jj;
    int kb = slab * 32 + (lane >> 4) * 8;
    #pragma unroll
    for (int p = 0; p < 4; ++p) {
        int k0 = kb + 2 * p, k1 = k0 + 1;
        float v0 = (k0 < K) ? W[(size_t)r * K + k0] : 0.f;
        float v1 = (k1 < K) ? W[(size_t)r * K + k1] : 0.f;
        dst[(size_t)idx * 4 + p] = (uint32)f2bf(v0) | ((uint32)f2bf(v1) << 16);
    }
}

__global__ void pack_kernel(const float* __restrict__ Wih0, const float* __restrict__ Whh0,
                            const float* __restrict__ bih0, const float* __restrict__ bhh0,
                            const float* __restrict__ Wih1, const float* __restrict__ Whh1,
                            const float* __restrict__ bih1, const float* __restrict__ bhh1,
                            uint32* __restrict__ wr0, uint32* __restrict__ wg0,
                            uint32* __restrict__ wr1, uint32* __restrict__ wg1,
                            float* __restrict__ b0p, float* __restrict__ b1p)
{
    const int C0 = NT_ * KSR_ * 64;   // 48000
    const int C1 = NT_ * 64;          // 4800
    int id = blockIdx.x * 256 + threadIdx.x;
    if (id < C0) pack_one(id, Whh0, H_, KSR_, wr0);
    else if (id < C0 + C1) pack_one(id - C0, Wih0, IN_, 1, wg0);
    else if (id < 2 * C0 + C1) pack_one(id - C0 - C1, Whh1, H_, KSR_, wr1);
    else if (id < 3 * C0 + C1) pack_one(id - 2 * C0 - C1, Wih1, H_, KSR_, wg1);
    else if (id < 3 * C0 + C1 + 1200) {
        int p = id - 3 * C0 - C1;
        int jj = p >> 2, g = p & 3, r = g * H_ + jj;
        b0p[p] = bih0[r] + bhh0[r];
    } else if (id < 3 * C0 + C1 + 2400) {
        int p = id - 3 * C0 - C1 - 1200;
        int jj = p >> 2, g = p & 3, r = g * H_ + jj;
        b1p[p] = bih1[r] + bhh1[r];
    }
}

// ---------------------------------------------------------------------------
// xg GEMM layer 0 (K=16): xg[(g*TC+tc)*NT + n][lane] = bias + Wih0 @ x_t
// ---------------------------------------------------------------------------
__global__ __launch_bounds__(256) void gemm_xg0(
    const float* __restrict__ x, const short8* __restrict__ wgp,
    const float* __restrict__ bp, f32x4* __restrict__ xg, int t0, int TC)
{
    const int tc = blockIdx.x, g = blockIdx.y;
    const int wave = threadIdx.x >> 6, lane = threadIdx.x & 63;
    const int m = lane & 15, oct = lane >> 4;

    short8 a0;
    if (oct < 2) {
        const float* xr = x + ((size_t)(g * 16 + m) * T_ + (t0 + tc)) * IN_ + oct * 8;
        short8 v;
        #pragma unroll
        for (int e = 0; e < 8; ++e) v[e] = (short)f2bf(xr[e]);
        a0 = v;
    } else {
        short8 z = {0, 0, 0, 0, 0, 0, 0, 0};
        a0 = z;
    }
    f32x4* xq = xg + ((size_t)g * TC + tc) * NT_ * 64 + lane;
    #pragma unroll
    for (int ti = 0; ti < 19; ++ti) {
        int n = wave + 4 * ti;
        if (n >= NT_) continue;
        f32x4 acc = *(const f32x4*)&bp[n * 16 + oct * 4];
        acc = __builtin_amdgcn_mfma_f32_16x16x32_bf16(wgp[(size_t)n * 64 + lane], a0, acc, 0, 0, 0);
        xq[(size_t)n * 64] = acc;
    }
}

// ---------------------------------------------------------------------------
// xg GEMM layer 1 (K=300): 8 waves/block = 8 timesteps sharing one weight
// stream through L1. grid (TC/8, 16).
// ---------------------------------------------------------------------------
__global__ __launch_bounds__(512) void gemm_xg1(
    const unsigned short* __restrict__ hin, const short8* __restrict__ wgp,
    const float* __restrict__ bp, f32x4* __restrict__ xg, int TC)
{
    const int wave = threadIdx.x >> 6, lane = threadIdx.x & 63;
    const int g = blockIdx.y, tc = blockIdx.x * 8 + wave;
    const int m = lane & 15, oct = lane >> 4;

    const unsigned short* hr = hin + ((size_t)(g * 16 + m) * TC + tc) * HP_ + oct * 8;
    short8 a[KSR_];
    #pragma unroll
    for (int s = 0; s < KSR_; ++s) a[s] = *(const short8*)(hr + s * 32);

    f32x4* xq = xg + ((size_t)g * TC + tc) * NT_ * 64 + lane;
    for (int n = 0; n < NT_; ++n) {
        f32x4 acc = *(const f32x4*)&bp[n * 16 + oct * 4];
        #pragma unroll
        for (int s = 0; s < KSR_; ++s)
            acc = __builtin_amdgcn_mfma_f32_16x16x32_bf16(wgp[((size_t)n * KSR_ + s) * 64 + lane],
                                                          a[s], acc, 0, 0, 0);
        xq[(size_t)n * 64] = acc;
    }
}

// ---------------------------------------------------------------------------
// Recurrent LSTM chunk, N-split: 128 blocks x 640 threads.
// blockIdx = member*16 + g. Wave w of member b owns tile b*10+w; Whh slice
// pinned in named registers. Exchange per step, all via IF$ (sc0 sc1 ops,
// coherent across XCDs, zero cache-maintenance instructions):
//   store h slice (sc0sc1) -> syncthreads (vmcnt drain) -> tid0 relaxed
//   atomic_add sc1 -> tid0 polls sc0sc1 until all 8 members arrived ->
//   syncthreads -> wave w stages slab w into LDS (sc0sc1 load) ->
//   syncthreads -> ds_read_b128 fragments.
// ---------------------------------------------------------------------------
__global__ __launch_bounds__(640) void lstm_rec(
    const short8* __restrict__ wp, const f32x4* __restrict__ xg,
    unsigned short* __restrict__ hout, float* __restrict__ cbuf,
    unsigned short* __restrict__ hx, int* __restrict__ cnt,
    int t0, int TC, size_t rowstride_b, int tbase)
{
    __shared__ short8 Alds[KSR_ * 64];   // 10KB staged h fragments

    const int tid = threadIdx.x;
    const int wave = tid >> 6, lane = tid & 63;
    const int g = blockIdx.x & 15, member = blockIdx.x >> 4;
    int wtile = member * WPB_ + wave;
    const bool act = (wtile < NT_);
    if (!act) wtile = NT_ - 1;            // clamp: compute garbage, store nothing
    const int m = lane & 15, oct = lane >> 4;

    int* cg = cnt + g * 16;               // 64B-strided counters
    unsigned short* hxg = hx + (size_t)g * 16384;   // 32KB/group; slot1 @ +8192

    // pinned weights: named scalars, unconditional restrict-loads -> hoisted
    const short8* wq = wp + (size_t)wtile * KSR_ * 64 + lane;
#define DECLW(i) short8 w##i = wq[i * 64];
    FORALL10(DECLW)
#undef DECLW

    float c = 0.f;
    if (act && t0 > 0) c = cbuf[((size_t)g * 80 + wtile) * 64 + lane];

    // stage h_{t0-1} (slot 1; zeroed by memset when t0==0) into LDS
    {
        const short8* sb = (const short8*)(hxg + 8192);
        Alds[wave * 64 + lane] = load16_cg(&sb[wave * 64 + lane]);
    }
    __syncthreads();
#define DECLA(i) short8 a##i = Alds[i * 64 + lane];
    FORALL10(DECLA)
#undef DECLA
    __builtin_amdgcn_sched_barrier(0);

    const f32x4* xgp = xg + ((size_t)g * TC * NT_ + wtile) * 64 + lane;
    const int jj = wtile * 4 + oct;
    const int fragaddr = (((jj >> 5) * 64 + ((jj >> 3) & 3) * 16 + m) << 3) + (jj & 7);
    unsigned short* st0 = hxg + fragaddr;
    unsigned short* st1 = hxg + 8192 + fragaddr;
    unsigned short* houtp = hout + (size_t)(g * 16 + m) * rowstride_b
                          + (size_t)tbase * HP_ + jj;

    f32x4 xgv = xgp[0];

    for (int tc_ = 0; tc_ < TC; ++tc_) {
        const int gt = t0 + tc_;
        // prefetch next step's xg early (hidden under MFMAs + drain)
        const int tnext = (tc_ + 1 < TC) ? tc_ + 1 : tc_;
        f32x4 xgn = xgp[(size_t)tnext * (NT_ * 64)];
        {
            f32x4 acc0 = {0.f, 0.f, 0.f, 0.f};
            f32x4 acc1 = {0.f, 0.f, 0.f, 0.f};
            acc0 = __builtin_amdgcn_mfma_f32_16x16x32_bf16(w0, a0, acc0, 0, 0, 0);
            acc1 = __builtin_amdgcn_mfma_f32_16x16x32_bf16(w1, a1, acc1, 0, 0, 0);
            acc0 = __builtin_amdgcn_mfma_f32_16x16x32_bf16(w2, a2, acc0, 0, 0, 0);
            acc1 = __builtin_amdgcn_mfma_f32_16x16x32_bf16(w3, a3, acc1, 0, 0, 0);
            acc0 = __builtin_amdgcn_mfma_f32_16x16x32_bf16(w4, a4, acc0, 0, 0, 0);
            acc1 = __builtin_amdgcn_mfma_f32_16x16x32_bf16(w5, a5, acc1, 0, 0, 0);
            acc0 = __builtin_amdgcn_mfma_f32_16x16x32_bf16(w6, a6, acc0, 0, 0, 0);
            acc1 = __builtin_amdgcn_mfma_f32_16x16x32_bf16(w7, a7, acc1, 0, 0, 0);
            acc0 = __builtin_amdgcn_mfma_f32_16x16x32_bf16(w8, a8, acc0, 0, 0, 0);
            acc1 = __builtin_amdgcn_mfma_f32_16x16x32_bf16(w9, a9, acc1, 0, 0, 0);
            float gi = sigm(acc0[0] + acc1[0] + xgv[0]);
            float gf = sigm(acc0[1] + acc1[1] + xgv[1]);
            float gg = tanh_f(acc0[2] + acc1[2] + xgv[2]);
            float go = sigm(acc0[3] + acc1[3] + xgv[3]);
            float cn = gf * c + gi * gg;
            c = cn;
            unsigned short hb = f2bf(go * tanh_f(cn));
            if (act) {
                store_short_cg((gt & 1) ? st1 : st0, hb);
                houtp[(size_t)tc_ * HP_] = hb;
            }
        }
        __syncthreads();   // vmcnt(0): h stores visible at IF$ before arrive
        if (tid == 0) atomic_inc_cg(cg);
        if (tc_ + 1 < TC) {
            if (tid == 0) {
                const int target = MEMB_ * (gt + 1);
                int iters = 0;
                while (load_cnt_cg(cg) < target) {
                    __builtin_amdgcn_s_sleep(1);
                    if (++iters > (1 << 22)) break;   // bailout: wrong > hung
                }
            }
            __syncthreads();   // all 8 members' h at IF$
            const short8* sb = (const short8*)((gt & 1) ? (hxg + 8192) : hxg);
            Alds[wave * 64 + lane] = load16_cg(&sb[wave * 64 + lane]);
            __syncthreads();
#define RELA(i) a##i = Alds[i * 64 + lane];
            FORALL10(RELA)
#undef RELA
            __builtin_amdgcn_sched_barrier(0);
            xgv = xgn;
        }
    }
    if (act) cbuf[((size_t)g * 80 + wtile) * 64 + lane] = c;
}

// ---------------------------------------------------------------------------
// MLP head: per-thread position; weights uniform (L1/L2-cached).
// ---------------------------------------------------------------------------
__global__ __launch_bounds__(256) void head_kernel(
    const unsigned short* __restrict__ h1,
    const float* __restrict__ W1, const float* __restrict__ b1,
    const float* __restrict__ W2, const float* __restrict__ b2,
    const float* __restrict__ W3, const float* __restrict__ b3,
    float* __restrict__ out)
{
    int pos = blockIdx.x * 256 + threadIdx.x;
    const unsigned short* hr = h1 + (size_t)pos * HP_;
    float t1[30];
    #pragma unroll
    for (int j = 0; j < 30; ++j) t1[j] = b1[j];
    for (int kc = 0; kc < H_; kc += 4) {
        uint32 u0 = *(const uint32*)(hr + kc);
        uint32 u1 = *(const uint32*)(hr + kc + 2);
        float h0v = bf2f((unsigned short)(u0 & 0xffffu));
        float h1v = bf2f((unsigned short)(u0 >> 16));
        float h2v = bf2f((unsigned short)(u1 & 0xffffu));
        float h3v = bf2f((unsigned short)(u1 >> 16));
        #pragma unroll
        for (int j = 0; j < 30; ++j) {
            const float* wr = W1 + j * H_ + kc;
            t1[j] += h0v * wr[0] + h1v * wr[1] + h2v * wr[2] + h3v * wr[3];
        }
    }
    #pragma unroll
    for (int j = 0; j < 30; ++j) t1[j] = tanh_f(t1[j]);
    float oacc = b3[0];
    for (int j2 = 0; j2 < 100; ++j2) {
        float a2 = b2[j2];
        #pragma unroll
        for (int k = 0; k < 30; ++k) a2 += t1[k] * W2[j2 * 30 + k];
        oacc += tanh_f(a2) * W3[j2];
    }
    out[pos] = sigm(oacc);
}

// ---------------------------------------------------------------------------
extern "C" void kernel_launch(void* const* d_in, const int* in_sizes, int n_in,
                              void* d_out, int out_size, void* d_ws, size_t ws_size,
                              hipStream_t stream)
{
    const float* x    = (const float*)d_in[0];
    const float* Wih0 = (const float*)d_in[1];
    const float* Whh0 = (const float*)d_in[2];
    const float* bih0 = (const float*)d_in[3];
    const float* bhh0 = (const float*)d_in[4];
    const float* Wih1 = (const float*)d_in[5];
    const float* Whh1 = (const float*)d_in[6];
    const float* bih1 = (const float*)d_in[7];
    const float* bhh1 = (const float*)d_in[8];
    const float* W1   = (const float*)d_in[9];
    const float* b1   = (const float*)d_in[10];
    const float* W2   = (const float*)d_in[11];
    const float* b2   = (const float*)d_in[12];
    const float* W3   = (const float*)d_in[13];
    const float* b3   = (const float*)d_in[14];

    char* ws = (char*)d_ws;
    const size_t OFF_WR0 = 0x000000;
    const size_t OFF_WG0 = 0x100000;
    const size_t OFF_WR1 = 0x200000;
    const size_t OFF_WG1 = 0x300000;
    const size_t OFF_B0  = 0x400000;
    const size_t OFF_B1  = 0x402000;
    const size_t OFF_CB0 = 0x500000;   // 320KB c-state L0
    const size_t OFF_CB1 = 0x550000;   // 320KB c-state L1
    const size_t OFF_HX0 = 0x5A0000;   // 512KB (16 groups x 32KB)
    const size_t OFF_HX1 = 0x620000;   // 512KB
    const size_t OFF_CNT = 0x6A0000;   // 8KB (cnt0 @ +0, cnt1 @ +4KB)
    const size_t OFF_H1  = 0x700000;
    const size_t H1_BYTES = (size_t)B_ * T_ * HP_ * 2;   // 40 MiB
    const size_t OFF_H0C  = OFF_H1 + H1_BYTES;

    int TC = 0;
    {
        const int cands[4] = {64, 32, 16, 8};
        for (int i = 0; i < 4; ++i) {
            size_t h0cb = (size_t)B_ * cands[i] * HP_ * 2;
            size_t xgb  = (size_t)16 * cands[i] * NT_ * 64 * 16;
            if (OFF_H0C + h0cb + xgb <= ws_size) { TC = cands[i]; break; }
        }
    }
    if (TC == 0) return;
    const size_t OFF_XG = OFF_H0C + (size_t)B_ * TC * HP_ * 2;

    uint32* wr0 = (uint32*)(ws + OFF_WR0);
    uint32* wg0 = (uint32*)(ws + OFF_WG0);
    uint32* wr1 = (uint32*)(ws + OFF_WR1);
    uint32* wg1 = (uint32*)(ws + OFF_WG1);
    float*  b0p = (float*)(ws + OFF_B0);
    float*  b1p = (float*)(ws + OFF_B1);
    float*  cb0 = (float*)(ws + OFF_CB0);
    float*  cb1 = (float*)(ws + OFF_CB1);
    unsigned short* hx0 = (unsigned short*)(ws + OFF_HX0);
    unsigned short* hx1 = (unsigned short*)(ws + OFF_HX1);
    int* cnt0 = (int*)(ws + OFF_CNT);
    int* cnt1 = (int*)(ws + OFF_CNT + 4096);
    unsigned short* h1b = (unsigned short*)(ws + OFF_H1);
    unsigned short* h0c = (unsigned short*)(ws + OFF_H0C);
    f32x4* xgb = (f32x4*)(ws + OFF_XG);

    // in-graph re-init each launch: h exchange slots, counters, h0c pads
    hipMemsetAsync(ws + OFF_HX0, 0, (OFF_CNT + 8192) - OFF_HX0, stream);
    hipMemsetAsync(ws + OFF_H0C, 0, (size_t)B_ * TC * HP_ * 2, stream);

    hipLaunchKernelGGL(pack_kernel, dim3(591), dim3(256), 0, stream,
                       Wih0, Whh0, bih0, bhh0, Wih1, Whh1, bih1, bhh1,
                       wr0, wg0, wr1, wg1, b0p, b1p);

    for (int t0 = 0; t0 < T_; t0 += TC) {
        hipLaunchKernelGGL(gemm_xg0, dim3(TC, 16), dim3(256), 0, stream,
                           x, (const short8*)wg0, b0p, xgb, t0, TC);
        hipLaunchKernelGGL(lstm_rec, dim3(128), dim3(640), 0, stream,
                           (const short8*)wr0, (const f32x4*)xgb, h0c, cb0, hx0, cnt0,
                           t0, TC, (size_t)TC * HP_, 0);
        hipLaunchKernelGGL(gemm_xg1, dim3(TC / 8, 16), dim3(512), 0, stream,
                           h0c, (const short8*)wg1, b1p, xgb, TC);
        hipLaunchKernelGGL(lstm_rec, dim3(128), dim3(640), 0, stream,
                           (const short8*)wr1, (const f32x4*)xgb, h1b, cb1, hx1, cnt1,
                           t0, TC, (size_t)T_ * HP_, t0);
    }
    hipLaunchKernelGGL(head_kernel, dim3(256), dim3(256), 0, stream,
                       h1b, W1, b1, W2, b2, W3, b3, (float*)d_out);
}